// Round 1
// baseline (325.716 us; speedup 1.0000x reference)
//
#include <hip/hip_runtime.h>
#include <math.h>

#define NQ 12
#define NL 6
#define BATCHN 8192
#define DIN 512

// Compile-time cycle decomposition of the register-half of the CNOT-chain
// permutation: dest reg r reads from src reg g6(r) = (r ^ (r<<1)) & 63.
struct PermPlan {
  signed char dst[64];
  signed char src[64];   // 64 => use saved temp (closes the cycle)
  bool save[64];         // save t = st[dst] before executing this op
};

constexpr int g6(int r) { return (r ^ (r << 1)) & 63; }

constexpr PermPlan make_plan() {
  PermPlan p{};
  bool vis[64] = {};
  int k = 0;
  for (int r0 = 0; r0 < 64; ++r0) {
    if (vis[r0]) continue;
    int r = r0;
    p.save[k] = true;
    for (;;) {
      int nr = g6(r);
      p.dst[k] = (signed char)r;
      p.src[k] = (signed char)(nr == r0 ? 64 : nr);
      vis[r] = true;
      ++k;
      if (nr == r0) break;
      r = nr;
    }
  }
  return p;
}

// One wave (64 lanes) per batch element. State: 4096 fp32 amplitudes,
// lane bits = wires 6..11, register bits = wires 0..5 (wire w = bit w of
// the flattened basis index, little-endian; relabeling is self-consistent).
__global__ void dqc_kernel(const float* __restrict__ x,
                           const float* __restrict__ pre_w,
                           const float* __restrict__ pre_b,
                           const float* __restrict__ weights,
                           const float* __restrict__ post_w,
                           const float* __restrict__ post_b,
                           float* __restrict__ out)
{
  const int lane = threadIdx.x & 63;
  const int wid  = threadIdx.x >> 6;
  const int b    = blockIdx.x * 4 + wid;

  // ---- stage per-layer gate trig in LDS (same for all batch elements)
  __shared__ float wcl[NL * NQ];
  __shared__ float wsl[NL * NQ];
  if (threadIdx.x < NL * NQ) {
    float h = 0.5f * weights[threadIdx.x];
    float sw, cw;
    sincosf(h, &sw, &cw);
    wcl[threadIdx.x] = cw;
    wsl[threadIdx.x] = sw;
  }
  __syncthreads();

  // ---- pre-GEMM: pre[w] = x[b,:] . pre_w[w,:] ; each lane does 8 columns
  float acc[NQ];
  const float* xr = x + (size_t)b * DIN + lane * 8;
  const float4 xa = *(const float4*)(xr);
  const float4 xb = *(const float4*)(xr + 4);
  #pragma unroll
  for (int w = 0; w < NQ; ++w) {
    const float* wr = pre_w + w * DIN + lane * 8;
    const float4 wa = *(const float4*)(wr);
    const float4 wb = *(const float4*)(wr + 4);
    acc[w] = xa.x * wa.x + xa.y * wa.y + xa.z * wa.z + xa.w * wa.w
           + xb.x * wb.x + xb.y * wb.y + xb.z * wb.z + xb.w * wb.w;
  }
  #pragma unroll
  for (int w = 0; w < NQ; ++w) {
    #pragma unroll
    for (int d = 1; d < 64; d <<= 1) acc[w] += __shfl_xor(acc[w], d, 64);
  }

  // ---- initial per-qubit vectors: h = 0.5 * (pre * pi/2) = pre * pi/4
  const float PI_4 = 0.78539816339744830962f;
  const float INV_SQRT2 = 0.70710678118654752440f;
  float v0[NQ], v1[NQ];
  #pragma unroll
  for (int w = 0; w < NQ; ++w) {
    float h = (acc[w] + pre_b[w]) * PI_4;
    float s, c;
    sincosf(h, &s, &c);
    v0[w] = (c - s) * INV_SQRT2;
    v1[w] = (c + s) * INV_SQRT2;
  }

  // ---- initial product state
  float lp = (((lane >> 0) & 1) ? v1[6]  : v0[6])
           * (((lane >> 1) & 1) ? v1[7]  : v0[7])
           * (((lane >> 2) & 1) ? v1[8]  : v0[8])
           * (((lane >> 3) & 1) ? v1[9]  : v0[9])
           * (((lane >> 4) & 1) ? v1[10] : v0[10])
           * (((lane >> 5) & 1) ? v1[11] : v0[11]);

  float st[64];
  #pragma unroll
  for (int r = 0; r < 64; ++r) {
    float p = lp;
    #pragma unroll
    for (int w = 0; w < 6; ++w) p *= ((r >> w) & 1) ? v1[w] : v0[w];
    st[r] = p;
  }

  // src lane for the CNOT-chain permutation: bits k>=1: l_k ^ l_{k-1};
  // bit 0: l_0 (further XORed with dest-reg bit 5 per op)
  const int glane = (lane ^ (lane << 1)) & 63;
  constexpr PermPlan P = make_plan();

  // ---- layers
  #pragma clang loop unroll(disable)
  for (int layer = 0; layer < NL; ++layer) {
    const int base = layer * NQ;

    // RY on register-bit wires 0..5 (in-register pairs)
    #pragma unroll
    for (int w = 0; w < 6; ++w) {
      const float cl = wcl[base + w];
      const float sl = wsl[base + w];
      const int m = 1 << w;
      #pragma unroll
      for (int r = 0; r < 64; ++r) {
        if (!(r & m)) {
          const float a0 = st[r];
          const float a1 = st[r | m];
          st[r]     = fmaf(-sl, a1, cl * a0);
          st[r | m] = fmaf( sl, a0, cl * a1);
        }
      }
    }

    // RY on lane-bit wires 6..11 (shfl_xor pairs)
    #pragma unroll
    for (int w = 6; w < NQ; ++w) {
      const float cl = wcl[base + w];
      const float sl = wsl[base + w];
      const int bm = 1 << (w - 6);
      const float sgn_s = (lane & bm) ? sl : -sl;
      #pragma unroll
      for (int r = 0; r < 64; ++r) {
        const float partner = __shfl_xor(st[r], bm, 64);
        st[r] = fmaf(sgn_s, partner, cl * st[r]);
      }
    }

    // CNOT chain (0,1)(1,2)...(10,11) == single permutation src = dst^(dst<<1)
    {
      float t = 0.f;
      #pragma unroll
      for (int k = 0; k < 64; ++k) {
        const int d = (int)P.dst[k];
        const int s = (int)P.src[k];
        if (P.save[k]) t = st[d];
        const float val = (s == 64) ? t : st[s];
        st[d] = __shfl(val, glane ^ ((d >> 5) & 1), 64);
      }
    }
  }

  // ---- measurement: z_w = sum(st^2 * (1 - 2*bit_w))
  #pragma unroll
  for (int r = 0; r < 64; ++r) st[r] *= st[r];

  float tot = 0.f;
  #pragma unroll
  for (int r = 0; r < 64; ++r) tot += st[r];

  float z[NQ];
  #pragma unroll
  for (int w = 0; w < 6; ++w) {
    float neg = 0.f;
    #pragma unroll
    for (int r = 0; r < 64; ++r) {
      if ((r >> w) & 1) neg += st[r];
    }
    z[w] = tot - 2.f * neg;
  }
  #pragma unroll
  for (int w = 6; w < NQ; ++w) {
    z[w] = ((lane >> (w - 6)) & 1) ? -tot : tot;
  }
  #pragma unroll
  for (int w = 0; w < NQ; ++w) {
    #pragma unroll
    for (int d = 1; d < 64; d <<= 1) z[w] += __shfl_xor(z[w], d, 64);
  }

  // ---- post-linear
  if (lane == 0) {
    float o = post_b[0];
    #pragma unroll
    for (int w = 0; w < NQ; ++w) o = fmaf(z[w], post_w[w], o);
    out[b] = o;
  }
}

extern "C" void kernel_launch(void* const* d_in, const int* in_sizes, int n_in,
                              void* d_out, int out_size, void* d_ws, size_t ws_size,
                              hipStream_t stream) {
  (void)in_sizes; (void)n_in; (void)out_size; (void)d_ws; (void)ws_size;
  const float* x       = (const float*)d_in[0];
  const float* pre_w   = (const float*)d_in[1];
  const float* pre_b   = (const float*)d_in[2];
  const float* weights = (const float*)d_in[3];
  const float* post_w  = (const float*)d_in[4];
  const float* post_b  = (const float*)d_in[5];
  float* out = (float*)d_out;

  dqc_kernel<<<BATCHN / 4, 256, 0, stream>>>(x, pre_w, pre_b, weights,
                                             post_w, post_b, out);
}

// Round 2
// 323.971 us; speedup vs baseline: 1.0054x; 1.0054x over previous
//
#include <hip/hip_runtime.h>
#include <math.h>

#define NQ 12
#define NL 6
#define BATCHN 8192
#define DIN 512

// Compile-time cycle decomposition of the register-half of the CNOT-chain
// permutation: dest reg r reads from src reg g6(r) = (r ^ (r<<1)) & 63.
struct PermPlan {
  signed char dst[64];
  signed char src[64];   // 64 => use saved temp (closes the cycle)
  bool save[64];         // save t = st[dst] before executing this op
};

constexpr int g6(int r) { return (r ^ (r << 1)) & 63; }

constexpr PermPlan make_plan() {
  PermPlan p{};
  bool vis[64] = {};
  int k = 0;
  for (int r0 = 0; r0 < 64; ++r0) {
    if (vis[r0]) continue;
    int r = r0;
    p.save[k] = true;
    for (;;) {
      int nr = g6(r);
      p.dst[k] = (signed char)r;
      p.src[k] = (signed char)(nr == r0 ? 64 : nr);
      vis[r] = true;
      ++k;
      if (nr == r0) break;
      r = nr;
    }
  }
  return p;
}

// One wave (64 lanes) per batch element. State: 4096 fp32 amplitudes,
// lane bits = wires 6..11, register bits = wires 0..5.
// __launch_bounds__(256,4): 4 waves/EU -> 128 VGPR budget. st[64]+temps
// (~95 peak) fits in arch VGPRs; without this the compiler targets 8
// waves/EU (56 VGPRs) and shuttles st[] through AGPRs (accvgpr_read/write
// around every gate FMA) -- that was the 290us regression in R0.
__global__ void __launch_bounds__(256, 4)
dqc_kernel(const float* __restrict__ x,
           const float* __restrict__ pre_w,
           const float* __restrict__ pre_b,
           const float* __restrict__ weights,
           const float* __restrict__ post_w,
           const float* __restrict__ post_b,
           float* __restrict__ out)
{
  const int lane = threadIdx.x & 63;
  const int wid  = threadIdx.x >> 6;
  const int b    = blockIdx.x * 4 + wid;

  // ---- stage per-layer gate trig in LDS (same for all batch elements)
  __shared__ float wcl[NL * NQ];
  __shared__ float wsl[NL * NQ];
  if (threadIdx.x < NL * NQ) {
    float h = 0.5f * weights[threadIdx.x];
    float sw, cw;
    sincosf(h, &sw, &cw);
    wcl[threadIdx.x] = cw;
    wsl[threadIdx.x] = sw;
  }
  __syncthreads();

  // ---- pre-GEMM: pre[w] = x[b,:] . pre_w[w,:] ; each lane does 8 columns
  float acc[NQ];
  const float* xr = x + (size_t)b * DIN + lane * 8;
  const float4 xa = *(const float4*)(xr);
  const float4 xb = *(const float4*)(xr + 4);
  #pragma unroll
  for (int w = 0; w < NQ; ++w) {
    const float* wr = pre_w + w * DIN + lane * 8;
    const float4 wa = *(const float4*)(wr);
    const float4 wb = *(const float4*)(wr + 4);
    acc[w] = xa.x * wa.x + xa.y * wa.y + xa.z * wa.z + xa.w * wa.w
           + xb.x * wb.x + xb.y * wb.y + xb.z * wb.z + xb.w * wb.w;
  }
  #pragma unroll
  for (int w = 0; w < NQ; ++w) {
    #pragma unroll
    for (int d = 1; d < 64; d <<= 1) acc[w] += __shfl_xor(acc[w], d, 64);
  }

  // ---- initial per-qubit vectors: h = 0.5 * (pre * pi/2) = pre * pi/4
  const float PI_4 = 0.78539816339744830962f;
  const float INV_SQRT2 = 0.70710678118654752440f;
  float v0[NQ], v1[NQ];
  #pragma unroll
  for (int w = 0; w < NQ; ++w) {
    float h = (acc[w] + pre_b[w]) * PI_4;
    float s, c;
    sincosf(h, &s, &c);
    v0[w] = (c - s) * INV_SQRT2;
    v1[w] = (c + s) * INV_SQRT2;
  }

  // ---- initial product state
  float lp = (((lane >> 0) & 1) ? v1[6]  : v0[6])
           * (((lane >> 1) & 1) ? v1[7]  : v0[7])
           * (((lane >> 2) & 1) ? v1[8]  : v0[8])
           * (((lane >> 3) & 1) ? v1[9]  : v0[9])
           * (((lane >> 4) & 1) ? v1[10] : v0[10])
           * (((lane >> 5) & 1) ? v1[11] : v0[11]);

  float st[64];
  #pragma unroll
  for (int r = 0; r < 64; ++r) {
    float p = lp;
    #pragma unroll
    for (int w = 0; w < 6; ++w) p *= ((r >> w) & 1) ? v1[w] : v0[w];
    st[r] = p;
  }

  // src lane for the CNOT-chain permutation
  const int glane = (lane ^ (lane << 1)) & 63;
  constexpr PermPlan P = make_plan();

  // ---- layers
  #pragma clang loop unroll(disable)
  for (int layer = 0; layer < NL; ++layer) {
    const int base = layer * NQ;

    // RY on register-bit wires 0..5 (in-register pairs)
    #pragma unroll
    for (int w = 0; w < 6; ++w) {
      const float cl = wcl[base + w];
      const float sl = wsl[base + w];
      const int m = 1 << w;
      #pragma unroll
      for (int r = 0; r < 64; ++r) {
        if (!(r & m)) {
          const float a0 = st[r];
          const float a1 = st[r | m];
          st[r]     = fmaf(-sl, a1, cl * a0);
          st[r | m] = fmaf( sl, a0, cl * a1);
        }
      }
    }

    // RY on lane-bit wires 6..11 (shfl_xor pairs)
    #pragma unroll
    for (int w = 6; w < NQ; ++w) {
      const float cl = wcl[base + w];
      const float sl = wsl[base + w];
      const int bm = 1 << (w - 6);
      const float sgn_s = (lane & bm) ? sl : -sl;
      #pragma unroll
      for (int r = 0; r < 64; ++r) {
        const float partner = __shfl_xor(st[r], bm, 64);
        st[r] = fmaf(sgn_s, partner, cl * st[r]);
      }
    }

    // CNOT chain (0,1)(1,2)...(10,11) == single permutation src = dst^(dst<<1)
    {
      float t = 0.f;
      #pragma unroll
      for (int k = 0; k < 64; ++k) {
        const int d = (int)P.dst[k];
        const int s = (int)P.src[k];
        if (P.save[k]) t = st[d];
        const float val = (s == 64) ? t : st[s];
        st[d] = __shfl(val, glane ^ ((d >> 5) & 1), 64);
      }
    }
  }

  // ---- measurement: z_w = sum(st^2 * (1 - 2*bit_w))
  #pragma unroll
  for (int r = 0; r < 64; ++r) st[r] *= st[r];

  float tot = 0.f;
  #pragma unroll
  for (int r = 0; r < 64; ++r) tot += st[r];

  float z[NQ];
  #pragma unroll
  for (int w = 0; w < 6; ++w) {
    float neg = 0.f;
    #pragma unroll
    for (int r = 0; r < 64; ++r) {
      if ((r >> w) & 1) neg += st[r];
    }
    z[w] = tot - 2.f * neg;
  }
  #pragma unroll
  for (int w = 6; w < NQ; ++w) {
    z[w] = ((lane >> (w - 6)) & 1) ? -tot : tot;
  }
  #pragma unroll
  for (int w = 0; w < NQ; ++w) {
    #pragma unroll
    for (int d = 1; d < 64; d <<= 1) z[w] += __shfl_xor(z[w], d, 64);
  }

  // ---- post-linear
  if (lane == 0) {
    float o = post_b[0];
    #pragma unroll
    for (int w = 0; w < NQ; ++w) o = fmaf(z[w], post_w[w], o);
    out[b] = o;
  }
}

extern "C" void kernel_launch(void* const* d_in, const int* in_sizes, int n_in,
                              void* d_out, int out_size, void* d_ws, size_t ws_size,
                              hipStream_t stream) {
  (void)in_sizes; (void)n_in; (void)out_size; (void)d_ws; (void)ws_size;
  const float* x       = (const float*)d_in[0];
  const float* pre_w   = (const float*)d_in[1];
  const float* pre_b   = (const float*)d_in[2];
  const float* weights = (const float*)d_in[3];
  const float* post_w  = (const float*)d_in[4];
  const float* post_b  = (const float*)d_in[5];
  float* out = (float*)d_out;

  dqc_kernel<<<BATCHN / 4, 256, 0, stream>>>(x, pre_w, pre_b, weights,
                                             post_w, post_b, out);
}

// Round 3
// 185.015 us; speedup vs baseline: 1.7605x; 1.7511x over previous
//
#include <hip/hip_runtime.h>
#include <math.h>

#define NQ 12
#define NL 6
#define BATCHN 8192
#define DIN 512

// Compile-time cycle decomposition of the register-half of the CNOT-chain
// permutation: dest reg r reads from src reg g6(r) = (r ^ (r<<1)) & 63.
struct PermPlan {
  signed char dst[64];
  signed char src[64];   // 64 => use saved temp (closes the cycle)
  bool save[64];         // save t = st[dst] before executing this op
};

constexpr int g6(int r) { return (r ^ (r << 1)) & 63; }

constexpr PermPlan make_plan() {
  PermPlan p{};
  bool vis[64] = {};
  int k = 0;
  for (int r0 = 0; r0 < 64; ++r0) {
    if (vis[r0]) continue;
    int r = r0;
    p.save[k] = true;
    for (;;) {
      int nr = g6(r);
      p.dst[k] = (signed char)r;
      p.src[k] = (signed char)(nr == r0 ? 64 : nr);
      vis[r] = true;
      ++k;
      if (nr == r0) break;
      r = nr;
    }
  }
  return p;
}

// ---- cross-lane helpers -------------------------------------------------
// xor-1 / xor-2 via DPP quad_perm: VALU pipe, zero DS traffic.
__device__ __forceinline__ float xor1_dpp(float v) {
  return __int_as_float(__builtin_amdgcn_mov_dpp(__float_as_int(v), 0xB1, 0xF, 0xF, false));
}
__device__ __forceinline__ float xor2_dpp(float v) {
  return __int_as_float(__builtin_amdgcn_mov_dpp(__float_as_int(v), 0x4E, 0xF, 0xF, false));
}
// xor-4/8/16 via ds_swizzle (BitMode: (xor<<10)|0x1F) -- DS pipe, no addr VGPR.
template <int PAT>
__device__ __forceinline__ float swz(float v) {
  return __int_as_float(__builtin_amdgcn_ds_swizzle(__float_as_int(v), PAT));
}
// arbitrary gather via ds_bpermute (addr in bytes)
__device__ __forceinline__ float bperm(int addr, float v) {
  return __int_as_float(__builtin_amdgcn_ds_bpermute(addr, __float_as_int(v)));
}

__device__ __forceinline__ float wave_sum(float v) {
  v += xor1_dpp(v);
  v += xor2_dpp(v);
  v += swz<0x101F>(v);
  v += swz<0x201F>(v);
  v += swz<0x401F>(v);
  v += __shfl_xor(v, 32, 64);
  return v;
}

// One wave (64 lanes) per batch element. State: 4096 fp32 amplitudes,
// lane bits = wires 6..11, register bits = wires 0..5.
//
// All 72 weight-gate cos factors are DEFERRED (gate = [[1,-t],[t,1]], t=tan):
// z_w = sum(+-u^2)/sum(u^2) is scale-invariant, so the global scale never
// needs applying. Initial (data-dependent) state stays exact/normalized so
// fp32 range is safe.
//
// amdgpu_waves_per_eu(4,4): pins the register budget at 128 arch VGPRs so
// st[64] lives in arch registers. R1 showed launch_bounds(256,4) alone
// leaves the allocator at 56 arch VGPRs + AGPR spill (accvgpr churn ~2.4x
// VALU inflation).
__global__ void __launch_bounds__(256)
__attribute__((amdgpu_waves_per_eu(4, 4)))
dqc_kernel(const float* __restrict__ x,
           const float* __restrict__ pre_w,
           const float* __restrict__ pre_b,
           const float* __restrict__ weights,
           const float* __restrict__ post_w,
           const float* __restrict__ post_b,
           float* __restrict__ out)
{
  const int lane = threadIdx.x & 63;
  const int wid  = threadIdx.x >> 6;
  const int b    = blockIdx.x * 4 + wid;

  // ---- stage per-gate tan(h) in LDS (same for all batch elements)
  __shared__ float wt[NL * NQ];
  if (threadIdx.x < NL * NQ) {
    wt[threadIdx.x] = tanf(0.5f * weights[threadIdx.x]);
  }
  __syncthreads();

  // ---- pre-GEMM: pre[w] = x[b,:] . pre_w[w,:] ; each lane does 8 columns
  float acc[NQ];
  const float* xr = x + (size_t)b * DIN + lane * 8;
  const float4 xa = *(const float4*)(xr);
  const float4 xb = *(const float4*)(xr + 4);
  #pragma unroll
  for (int w = 0; w < NQ; ++w) {
    const float* wr = pre_w + w * DIN + lane * 8;
    const float4 wa = *(const float4*)(wr);
    const float4 wb = *(const float4*)(wr + 4);
    acc[w] = xa.x * wa.x + xa.y * wa.y + xa.z * wa.z + xa.w * wa.w
           + xb.x * wb.x + xb.y * wb.y + xb.z * wb.z + xb.w * wb.w;
  }
  #pragma unroll
  for (int w = 0; w < NQ; ++w) acc[w] = wave_sum(acc[w]);

  // ---- initial per-qubit vectors: h = 0.5 * (pre * pi/2) = pre * pi/4
  const float PI_4 = 0.78539816339744830962f;
  const float INV_SQRT2 = 0.70710678118654752440f;
  float v0[NQ], v1[NQ];
  #pragma unroll
  for (int w = 0; w < NQ; ++w) {
    float h = (acc[w] + pre_b[w]) * PI_4;
    float s, c;
    sincosf(h, &s, &c);
    v0[w] = (c - s) * INV_SQRT2;
    v1[w] = (c + s) * INV_SQRT2;
  }

  // ---- initial product state
  float lp = (((lane >> 0) & 1) ? v1[6]  : v0[6])
           * (((lane >> 1) & 1) ? v1[7]  : v0[7])
           * (((lane >> 2) & 1) ? v1[8]  : v0[8])
           * (((lane >> 3) & 1) ? v1[9]  : v0[9])
           * (((lane >> 4) & 1) ? v1[10] : v0[10])
           * (((lane >> 5) & 1) ? v1[11] : v0[11]);

  float st[64];
  #pragma unroll
  for (int r = 0; r < 64; ++r) {
    float p = lp;
    #pragma unroll
    for (int w = 0; w < 6; ++w) p *= ((r >> w) & 1) ? v1[w] : v0[w];
    st[r] = p;
  }

  // precomputed bpermute byte-addresses (loop-invariant)
  const int a32   = ((lane ^ 32) << 2);                 // xor-32 exchange
  const int glane = (lane ^ (lane << 1)) & 63;          // CNOT-chain lane gather
  const int aglA  = (glane << 2);
  const int aglB  = ((glane ^ 1) << 2);
  constexpr PermPlan P = make_plan();

  // ---- layers
  #pragma clang loop unroll(disable)
  for (int layer = 0; layer < NL; ++layer) {
    const int base = layer * NQ;

    // RY (tan form) on register-bit wires 0..5: in-register pairs, 2 fma/pair
    #pragma unroll
    for (int w = 0; w < 6; ++w) {
      const float t = wt[base + w];
      const int m = 1 << w;
      #pragma unroll
      for (int r = 0; r < 64; ++r) {
        if (!(r & m)) {
          const float a0 = st[r];
          const float a1 = st[r | m];
          st[r]     = fmaf(-t, a1, a0);
          st[r | m] = fmaf( t, a0, a1);
        }
      }
    }

    // RY (tan form) on lane-bit wires 6..11: partner exchange + 1 fma
    {
      // wire 6 (xor-1) via DPP
      const float t = wt[base + 6];
      const float ts = (lane & 1) ? t : -t;
      #pragma unroll
      for (int r = 0; r < 64; ++r) st[r] = fmaf(ts, xor1_dpp(st[r]), st[r]);
    }
    {
      // wire 7 (xor-2) via DPP
      const float t = wt[base + 7];
      const float ts = (lane & 2) ? t : -t;
      #pragma unroll
      for (int r = 0; r < 64; ++r) st[r] = fmaf(ts, xor2_dpp(st[r]), st[r]);
    }
    {
      const float t = wt[base + 8];
      const float ts = (lane & 4) ? t : -t;
      #pragma unroll
      for (int r = 0; r < 64; ++r) st[r] = fmaf(ts, swz<0x101F>(st[r]), st[r]);
    }
    {
      const float t = wt[base + 9];
      const float ts = (lane & 8) ? t : -t;
      #pragma unroll
      for (int r = 0; r < 64; ++r) st[r] = fmaf(ts, swz<0x201F>(st[r]), st[r]);
    }
    {
      const float t = wt[base + 10];
      const float ts = (lane & 16) ? t : -t;
      #pragma unroll
      for (int r = 0; r < 64; ++r) st[r] = fmaf(ts, swz<0x401F>(st[r]), st[r]);
    }
    {
      const float t = wt[base + 11];
      const float ts = (lane & 32) ? t : -t;
      #pragma unroll
      for (int r = 0; r < 64; ++r) st[r] = fmaf(ts, bperm(a32, st[r]), st[r]);
    }

    // CNOT chain (0,1)(1,2)...(10,11) == single permutation src = dst^(dst<<1)
    {
      float tmp = 0.f;
      #pragma unroll
      for (int k = 0; k < 64; ++k) {
        const int d = (int)P.dst[k];
        const int s = (int)P.src[k];
        if (P.save[k]) tmp = st[d];
        const float val = (s == 64) ? tmp : st[s];
        st[d] = bperm((d & 32) ? aglB : aglA, val);
      }
    }
  }

  // ---- measurement: z_w = sum(st^2 * +-1) / sum(st^2)  (scale-invariant)
  #pragma unroll
  for (int r = 0; r < 64; ++r) st[r] *= st[r];

  float tot = 0.f;
  #pragma unroll
  for (int r = 0; r < 64; ++r) tot += st[r];

  float z[NQ];
  #pragma unroll
  for (int w = 0; w < 6; ++w) {
    float neg = 0.f;
    #pragma unroll
    for (int r = 0; r < 64; ++r) {
      if ((r >> w) & 1) neg += st[r];
    }
    z[w] = tot - 2.f * neg;
  }
  #pragma unroll
  for (int w = 6; w < NQ; ++w) {
    z[w] = ((lane >> (w - 6)) & 1) ? -tot : tot;
  }

  float tot_s = wave_sum(tot);
  #pragma unroll
  for (int w = 0; w < NQ; ++w) z[w] = wave_sum(z[w]);

  // ---- post-linear
  if (lane == 0) {
    const float inv = 1.0f / tot_s;
    float o = post_b[0];
    #pragma unroll
    for (int w = 0; w < NQ; ++w) o = fmaf(z[w] * inv, post_w[w], o);
    out[b] = o;
  }
}

extern "C" void kernel_launch(void* const* d_in, const int* in_sizes, int n_in,
                              void* d_out, int out_size, void* d_ws, size_t ws_size,
                              hipStream_t stream) {
  (void)in_sizes; (void)n_in; (void)out_size; (void)d_ws; (void)ws_size;
  const float* x       = (const float*)d_in[0];
  const float* pre_w   = (const float*)d_in[1];
  const float* pre_b   = (const float*)d_in[2];
  const float* weights = (const float*)d_in[3];
  const float* post_w  = (const float*)d_in[4];
  const float* post_b  = (const float*)d_in[5];
  float* out = (float*)d_out;

  dqc_kernel<<<BATCHN / 4, 256, 0, stream>>>(x, pre_w, pre_b, weights,
                                             post_w, post_b, out);
}